// Round 19
// baseline (508.669 us; speedup 1.0000x reference)
//
#include <hip/hip_runtime.h>

#define BB 128
#define SS 512
#define TT 513
#define DD 128
#define HH 4
#define LL 4
#define MM (BB*TT)   // 65664

typedef __attribute__((ext_vector_type(4))) float f32x4;
typedef __attribute__((ext_vector_type(16))) float f32x16;
typedef __attribute__((ext_vector_type(8))) short short8;

typedef const __attribute__((address_space(1))) char* gas_t;
typedef __attribute__((address_space(3))) char* las_t;
#define GLDS16(g, l) __builtin_amdgcn_global_load_lds((gas_t)(g), (las_t)(l), 16, 0, 0)

__device__ __forceinline__ float b2f(ushort u){
  union { uint i; float f; } c; c.i = ((uint)u) << 16; return c.f;
}
__device__ __forceinline__ ushort f2b(float f){
  union { float f; uint i; } c; c.f = f;
  uint x = c.i;
  return (ushort)((x + 0x7fffu + ((x >> 16) & 1u)) >> 16);
}
union S8 { short8 v; ushort u[8]; };

__device__ __forceinline__ uint cvtpk(float lo, float hi){
  uint r;
  asm("v_cvt_pk_bf16_f32 %0, %1, %2" : "=v"(r) : "v"(lo), "v"(hi));
  return r;
}
__device__ __forceinline__ float fexp2(float x){
#if __has_builtin(__builtin_amdgcn_exp2f)
  return __builtin_amdgcn_exp2f(x);
#else
  return exp2f(x);
#endif
}

// ---------------- embed ----------------
__global__ __launch_bounds__(256) void k_embed(
    const float* __restrict__ d_t, const float* __restrict__ d_l, const int* __restrict__ d_emb,
    const float* __restrict__ poi, const float* __restrict__ W_time, const float* __restrict__ W_space,
    const float* __restrict__ agg, ushort* __restrict__ xb)
{
  int gid = blockIdx.x*256 + threadIdx.x;
  if (gid >= MM*DD) return;
  int d = gid & 127;
  int m = gid >> 7;
  int b = m / TT, t = m % TT;
  float v;
  if (t == SS) v = agg[d];
  else {
    int bs = b*SS + t;
    v = d_t[bs]*W_time[d] + d_l[bs*2]*W_space[d*2] + d_l[bs*2+1]*W_space[d*2+1]
        + poi[(size_t)d_emb[bs]*DD + d];
  }
  xb[gid] = f2b(v);
}

// ---------------- fused f32 -> bf16 convert ----------------
__global__ __launch_bounds__(256) void k_f2b5(
    const float* __restrict__ s0, ushort* __restrict__ o0, int n0,
    const float* __restrict__ s1, ushort* __restrict__ o1, int n1,
    const float* __restrict__ s2, ushort* __restrict__ o2, int n2,
    const float* __restrict__ s3, ushort* __restrict__ o3, int n3,
    const float* __restrict__ s4, ushort* __restrict__ o4, int n4)
{
  int i = blockIdx.x*256 + threadIdx.x;
  if (i < n0){ o0[i] = f2b(s0[i]); return; } i -= n0;
  if (i < n1){ o1[i] = f2b(s1[i]); return; } i -= n1;
  if (i < n2){ o2[i] = f2b(s2[i]); return; } i -= n2;
  if (i < n3){ o3[i] = f2b(s3[i]); return; } i -= n3;
  if (i < n4){ o4[i] = f2b(s4[i]); }
}

// ---------------- GEMM v5 (K=128): 128-row tile, double-buffered W prefetch (qkv) ----------
template<bool RELU>
__global__ __launch_bounds__(512) void k_gemm2(
  const ushort* __restrict__ A, const ushort* __restrict__ W,
  const float* __restrict__ bias, ushort* __restrict__ Cout, const int N)
{
  __shared__ __align__(16) ushort As[128*128], Ws[2][64*128];
  const int tid = threadIdx.x;
  const int m0 = blockIdx.x * 128;
  const int l = tid & 63, wid = tid >> 6;
  const int wr = wid >> 1, wc = wid & 1;
  const int lr = l & 15, lg = l >> 4;
  #pragma unroll
  for (int i = tid; i < 2048; i += 512){
    const int row = i >> 4;
    const int ch  = (((i & 15)*16) ^ ((row & 7) << 4)) >> 4;
    GLDS16(&A[(size_t)(m0+row)*128 + ch*8], (char*)As + (size_t)(i - l)*16);
  }
  #pragma unroll
  for (int i = tid; i < 1024; i += 512){
    const int row = i >> 4;
    const int ch  = (((i & 15)*16) ^ ((row & 7) << 4)) >> 4;
    GLDS16(&W[(size_t)row*128 + ch*8], (char*)Ws[0] + (size_t)(i - l)*16);
  }
  __syncthreads();
  int buf = 0;
  for (int n0 = 0; n0 < N; n0 += 64){
    if (n0 + 64 < N){
      #pragma unroll
      for (int i = tid; i < 1024; i += 512){
        const int row = i >> 4;
        const int ch  = (((i & 15)*16) ^ ((row & 7) << 4)) >> 4;
        GLDS16(&W[(size_t)(n0+64+row)*128 + ch*8], (char*)Ws[buf^1] + (size_t)(i - l)*16);
      }
    }
    f32x4 acc[2][2] = {};
    #pragma unroll
    for (int k0 = 0; k0 < 128; k0 += 32){
      const int sw = ((k0 + lg*8)*2) ^ ((lr & 7) << 4);
      short8 a0 = *(const short8*)((const char*)As + (wr*32+lr)*256 + sw);
      short8 a1 = *(const short8*)((const char*)As + (wr*32+16+lr)*256 + sw);
      short8 b0 = *(const short8*)((const char*)Ws[buf] + (wc*32+lr)*256 + sw);
      short8 b1 = *(const short8*)((const char*)Ws[buf] + (wc*32+16+lr)*256 + sw);
      acc[0][0] = __builtin_amdgcn_mfma_f32_16x16x32_bf16(a0, b0, acc[0][0], 0,0,0);
      acc[0][1] = __builtin_amdgcn_mfma_f32_16x16x32_bf16(a0, b1, acc[0][1], 0,0,0);
      acc[1][0] = __builtin_amdgcn_mfma_f32_16x16x32_bf16(a1, b0, acc[1][0], 0,0,0);
      acc[1][1] = __builtin_amdgcn_mfma_f32_16x16x32_bf16(a1, b1, acc[1][1], 0,0,0);
    }
    #pragma unroll
    for (int i=0;i<2;i++)
    #pragma unroll
    for (int j=0;j<2;j++)
    #pragma unroll
    for (int r=0;r<4;r++){
      const int lm = wr*32 + i*16 + lg*4 + r;
      const int ln = n0 + wc*32 + j*16 + lr;
      float v = acc[i][j][r] + bias[ln];
      if (RELU) v = fmaxf(v, 0.f);
      Cout[(size_t)(m0+lm)*N + ln] = f2b(v);
    }
    __syncthreads();   // drains prefetch vmcnt; protects Ws[buf] reuse
    buf ^= 1;
  }
}

// ---------------- fused GEMM (N=128, K=128) + residual(bf16) + LayerNorm (o-proj) ----------
__global__ __launch_bounds__(512) void k_gemm_ln(
  const ushort* __restrict__ A, const ushort* __restrict__ W,
  const float* __restrict__ bias, ushort* __restrict__ xb,
  const float* __restrict__ g, const float* __restrict__ bb, const int K)
{
  __shared__ __align__(16) ushort As[128*128], Ws[128*128];
  const int tid = threadIdx.x;
  const int m0 = blockIdx.x * 128;
  const int l = tid & 63, w = tid >> 6;
  const int lr = l & 15, lg = l >> 4;
  f32x4 acc[8] = {};
  for (int kt = 0; kt < K; kt += 128){
    if (kt) __syncthreads();
    #pragma unroll
    for (int i = tid; i < 2048; i += 512){
      const int row = i >> 4;
      const int ch  = (((i & 15)*16) ^ ((row & 7) << 4)) >> 4;
      GLDS16(&A[(size_t)(m0+row)*K + kt + ch*8], (char*)As + (size_t)(i - l)*16);
    }
    #pragma unroll
    for (int i = tid; i < 2048; i += 512){
      const int row = i >> 4;
      const int ch  = (((i & 15)*16) ^ ((row & 7) << 4)) >> 4;
      GLDS16(&W[(size_t)row*K + kt + ch*8], (char*)Ws + (size_t)(i - l)*16);
    }
    __syncthreads();
    #pragma unroll
    for (int k0 = 0; k0 < 128; k0 += 32){
      const int sw = ((k0 + lg*8)*2) ^ ((lr & 7) << 4);
      short8 a = *(const short8*)((const char*)As + (w*16+lr)*256 + sw);
      #pragma unroll
      for (int j=0;j<8;j++){
        short8 bf = *(const short8*)((const char*)Ws + (j*16+lr)*256 + sw);
        acc[j] = __builtin_amdgcn_mfma_f32_16x16x32_bf16(a, bf, acc[j], 0,0,0);
      }
    }
  }
  float biasj[8], gj[8], bj[8];
  #pragma unroll
  for (int j=0;j<8;j++){ biasj[j]=bias[j*16+lr]; gj[j]=g[j*16+lr]; bj[j]=bb[j*16+lr]; }
  #pragma unroll
  for (int r=0;r<4;r++){
    const size_t row = (size_t)(m0 + w*16 + lg*4 + r);
    float resid[8], s=0.f, sq=0.f;
    #pragma unroll
    for (int j=0;j<8;j++){
      float v = acc[j][r] + biasj[j];
      resid[j] = b2f(xb[row*128 + j*16 + lr]) + v;
      s += resid[j]; sq += resid[j]*resid[j];
    }
    #pragma unroll
    for (int off=1; off<16; off<<=1){ s += __shfl_xor(s,off,64); sq += __shfl_xor(sq,off,64); }
    const float mean = s*(1.f/128.f);
    const float var  = fmaxf(sq*(1.f/128.f) - mean*mean, 0.f);
    const float rstd = rsqrtf(var + 1e-5f);
    #pragma unroll
    for (int j=0;j<8;j++){
      float o = (resid[j]-mean)*rstd*gj[j] + bj[j];
      xb[row*128 + j*16 + lr] = f2b(o);
    }
  }
}

// ---------------- fused FFN ----------------
__global__ __launch_bounds__(512) void k_ffn(
  const ushort* __restrict__ A, const ushort* __restrict__ W1, const float* __restrict__ b1,
  const ushort* __restrict__ W2, const float* __restrict__ b2,
  ushort* __restrict__ xb, const float* __restrict__ g, const float* __restrict__ bb)
{
  __shared__ __align__(16) ushort As[128*128];   // 32 KB
  __shared__ __align__(16) ushort W1s[64*128];   // 16 KB
  __shared__ __align__(16) ushort W2s[128*64];   // 16 KB
  __shared__ __align__(16) ushort Hs[128*64];    // 16 KB
  const int tid = threadIdx.x;
  const int m0 = blockIdx.x * 128;
  const int l = tid & 63, w = tid >> 6;
  const int lr = l & 15, lg = l >> 4;
  #pragma unroll
  for (int i = tid; i < 2048; i += 512){
    const int row = i >> 4;
    const int ch  = (((i & 15)*16) ^ ((row & 7) << 4)) >> 4;
    GLDS16(&A[(size_t)(m0+row)*128 + ch*8], (char*)As + (size_t)(i - l)*16);
  }
  f32x4 acc2[8] = {};
  for (int c = 0; c < 4; c++){
    __syncthreads();
    #pragma unroll
    for (int i = tid; i < 1024; i += 512){
      const int row = i >> 4;
      const int ch  = (((i & 15)*16) ^ ((row & 7) << 4)) >> 4;
      GLDS16(&W1[(size_t)(c*64+row)*128 + ch*8], (char*)W1s + (size_t)(i - l)*16);
    }
    #pragma unroll
    for (int i = tid; i < 1024; i += 512){
      const int row = i >> 3;
      const int ch  = (i & 7) ^ (row & 7);
      GLDS16(&W2[(size_t)row*256 + c*64 + ch*8], (char*)W2s + (size_t)(i - l)*16);
    }
    __syncthreads();
    f32x4 acc1[4] = {};
    #pragma unroll
    for (int k0 = 0; k0 < 128; k0 += 32){
      const int sw = ((k0 + lg*8)*2) ^ ((lr & 7) << 4);
      short8 a = *(const short8*)((const char*)As + (w*16+lr)*256 + sw);
      #pragma unroll
      for (int j=0;j<4;j++){
        short8 bf = *(const short8*)((const char*)W1s + (j*16+lr)*256 + sw);
        acc1[j] = __builtin_amdgcn_mfma_f32_16x16x32_bf16(a, bf, acc1[j], 0,0,0);
      }
    }
    #pragma unroll
    for (int j=0;j<4;j++){
      const float b1j = b1[c*64 + j*16 + lr];
      #pragma unroll
      for (int r=0;r<4;r++){
        const int row = w*16 + lg*4 + r;
        const int col = j*16 + lr;
        const float v = fmaxf(acc1[j][r] + b1j, 0.f);
        *(ushort*)((char*)Hs + ((row*128 + col*2) ^ ((row & 7) << 4))) = f2b(v);
      }
    }
    __syncthreads();
    #pragma unroll
    for (int kk=0; kk<2; kk++){
      const int sw2 = (kk*32 + lg*8)*2;
      short8 ha = *(const short8*)((const char*)Hs + (((w*16+lr)*128 + sw2) ^ ((lr & 7) << 4)));
      #pragma unroll
      for (int j=0;j<8;j++){
        short8 wf = *(const short8*)((const char*)W2s + (((j*16+lr)*128 + sw2) ^ ((lr & 7) << 4)));
        acc2[j] = __builtin_amdgcn_mfma_f32_16x16x32_bf16(ha, wf, acc2[j], 0,0,0);
      }
    }
  }
  float biasj[8], gj[8], bj[8];
  #pragma unroll
  for (int j=0;j<8;j++){ biasj[j]=b2[j*16+lr]; gj[j]=g[j*16+lr]; bj[j]=bb[j*16+lr]; }
  #pragma unroll
  for (int r=0;r<4;r++){
    const int rl = w*16 + lg*4 + r;
    const size_t row = (size_t)(m0 + rl);
    float resid[8], s=0.f, sq=0.f;
    #pragma unroll
    for (int j=0;j<8;j++){
      const float v = acc2[j][r] + biasj[j];
      const ushort xu = *(const ushort*)((const char*)As + ((rl*256 + (j*16+lr)*2) ^ ((rl & 7) << 4)));
      resid[j] = b2f(xu) + v;
      s += resid[j]; sq += resid[j]*resid[j];
    }
    #pragma unroll
    for (int off=1; off<16; off<<=1){ s += __shfl_xor(s,off,64); sq += __shfl_xor(sq,off,64); }
    const float mean = s*(1.f/128.f);
    const float var  = fmaxf(sq*(1.f/128.f) - mean*mean, 0.f);
    const float rstd = rsqrtf(var + 1e-5f);
    #pragma unroll
    for (int j=0;j<8;j++){
      const float o = (resid[j]-mean)*rstd*gj[j] + bj[j];
      xb[row*128 + j*16 + lr] = f2b(o);
    }
  }
}

// ---------------- flash attention v5c: + setprio around MFMA clusters ----------------
#define VSTRIDE 544
#define NEGM 30000.f
#define MFMA32(a,b,c) __builtin_amdgcn_mfma_f32_32x32x16_bf16(a,b,c,0,0,0)

__global__ __launch_bounds__(512) void k_attn(const ushort* __restrict__ qkv, ushort* __restrict__ ao)
{
  __shared__ __align__(16) ushort KL[VSTRIDE*32];
  __shared__ __align__(16) ushort VT[32*VSTRIDE];
  const int tid = threadIdx.x;
  const int b = blockIdx.x >> 2, h = blockIdx.x & 3;
  const size_t base = (size_t)b*TT*384 + h*32;
  union { short4 v; ushort u[4]; } sv;
  for (int i = tid; i < 8*VSTRIDE; i += 512){
    int t = i >> 3, dc = (i & 7)*4;
    sv.u[0]=0; sv.u[1]=0; sv.u[2]=0; sv.u[3]=0;
    if (t < TT) sv.v = *(const short4*)&qkv[base + (size_t)t*384 + 128 + dc];
    *(short4*)((char*)KL + ((t*64 + dc*2) ^ ((t&7)<<4))) = sv.v;
  }
  for (int i = tid; i < 8*VSTRIDE; i += 512){
    int t = i >> 3, dc = (i & 7)*4;
    sv.u[0]=0; sv.u[1]=0; sv.u[2]=0; sv.u[3]=0;
    if (t < TT) sv.v = *(const short4*)&qkv[base + (size_t)t*384 + 256 + dc];
    #pragma unroll
    for (int e=0;e<4;e++){
      int d = dc + e;
      *(ushort*)((char*)VT + ((d*1088 + t*2) ^ ((d&7)<<4))) = sv.u[e];
    }
  }
  __syncthreads();
  const int l = tid & 63, w = tid >> 6;
  const int lq = l & 31, hi = l >> 5;
  const float qscale = 0.25503486341f;
  const int krow = (lq & 3) | ((lq & 4) << 1) | ((lq & 8) >> 1) | (lq & 16);
  f32x16 cinit;
  #pragma unroll
  for (int r=0;r<16;r++) cinit[r] = -40.f;

  for (int qi = 0; qi < 3; qi++){
    const int qb = w + qi*8;
    if (qb >= 17) break;
    const int q0 = qb*32;
    int qrow = q0 + lq; if (qrow > SS) qrow = SS;
    S8 qa, qf0, qf1;
    qa.v = *(const short8*)&qkv[base + (size_t)qrow*384 + hi*8];
    #pragma unroll
    for (int j=0;j<8;j++) qf0.u[j] = f2b(b2f(qa.u[j]) * qscale);
    qa.v = *(const short8*)&qkv[base + (size_t)qrow*384 + 16 + hi*8];
    #pragma unroll
    for (int j=0;j<8;j++) qf1.u[j] = f2b(b2f(qa.u[j]) * qscale);

    float rsl = 0.f;
    f32x16 acc = {};
    int t0 = 0;
    for (int kb = 0; kb < 17; kb++, t0 += 32){
      const int trow = t0 + krow;
      short8 kc0 = *(const short8*)((const char*)KL + ((trow*64 + hi*16)      ^ ((trow&7)<<4)));
      short8 kc1 = *(const short8*)((const char*)KL + ((trow*64 + 32 + hi*16) ^ ((trow&7)<<4)));
      __builtin_amdgcn_s_setprio(1);
      f32x16 s = MFMA32(kc0, qf0.v, cinit);
      s = MFMA32(kc1, qf1.v, s);
      __builtin_amdgcn_s_setprio(0);
      if (t0 + 32 > TT){
        #pragma unroll
        for (int r=0;r<16;r++){
          const int key = t0 + (r&7) + 8*hi + 16*(r>>3);
          if (key >= TT) s[r] = -NEGM;
        }
      }
      float p[16];
      #pragma unroll
      for (int r=0;r<16;r++){ p[r] = fexp2(s[r]); rsl += p[r]; }
      union { short8 v; uint u[4]; } pa0, pa1;
      #pragma unroll
      for (int wd=0; wd<4; wd++){
        pa0.u[wd] = cvtpk(p[2*wd],   p[2*wd+1]);
        pa1.u[wd] = cvtpk(p[8+2*wd], p[8+2*wd+1]);
      }
      short8 v0 = *(const short8*)((const char*)VT + (((lq*1088) + (t0 + hi*8)*2)      ^ ((lq&7)<<4)));
      short8 v1 = *(const short8*)((const char*)VT + (((lq*1088) + (t0 + 16 + hi*8)*2) ^ ((lq&7)<<4)));
      __builtin_amdgcn_s_setprio(1);
      acc = MFMA32(v0, pa0.v, acc);
      acc = MFMA32(v1, pa1.v, acc);
      __builtin_amdgcn_s_setprio(0);
    }
    rsl += __shfl_xor(rsl, 32, 64);
    if (q0 + lq < TT){
      const float inv = 1.f / rsl;
      ushort* orow = ao + ((size_t)(b*TT + q0 + lq))*DD + h*32;
      #pragma unroll
      for (int r=0;r<16;r++){
        const int d = (r&3) + 8*(r>>2) + 4*hi;
        orow[d] = f2b(acc[r]*inv);
      }
    }
  }
}

// ---------------- ctx extraction + gamma/tau heads ----------------
__global__ __launch_bounds__(256) void k_ctx(
    const ushort* __restrict__ xb, const float* __restrict__ Wg, const float* __restrict__ bg,
    const float* __restrict__ Wt, const float* __restrict__ bt,
    float* __restrict__ out, float* __restrict__ ctxws)
{
  __shared__ float cs[128];
  const int b = blockIdx.x, tid = threadIdx.x;
  const ushort* xr = &xb[((size_t)b*TT + SS)*128];
  if (tid < 128){
    float v = b2f(xr[tid]);
    cs[tid] = v;
    out[(size_t)b*419 + 34 + tid] = v;
    ctxws[b*128 + tid] = v;
  }
  __syncthreads();
  const int j = tid & 127;
  const float* Wrow = (tid < 128) ? &Wg[(size_t)j*128] : &Wt[(size_t)j*128];
  float acc = 0.f;
  #pragma unroll 8
  for (int d=0; d<128; d+=4){
    float4 wv = *(const float4*)&Wrow[d];
    acc += cs[d]*wv.x + cs[d+1]*wv.y + cs[d+2]*wv.z + cs[d+3]*wv.w;
  }
  if (tid < 128){
    out[(size_t)b*419 + 162 + j] = acc + bg[j];
  } else {
    float tv = acc + bt[j];
    float sp = fmaxf(tv, 0.f) + log1pf(__expf(-fabsf(tv)));
    out[(size_t)b*419 + 290 + j] = sp;
  }
}

// ---------------- GRU decoder v8: Whh B-frags in LDS (kills spill), MFMA-batched ----------
#define GB 16
__global__ __launch_bounds__(512, 1) void k_gru(
    const float* __restrict__ ctx, const ushort* __restrict__ whh_b,
    const float* __restrict__ bih, const float* __restrict__ bhh,
    const float* __restrict__ Wfc, const float* __restrict__ bfc,
    float* __restrict__ deltas)
{
  __shared__ __align__(16) ushort WL[384*128];  // 96 KB, swizzled like GEMM Ws
  __shared__ __align__(16) uint hb2[16*68];
  __shared__ __align__(16) float ghs[16*388];
  __shared__ float red[GB];
  const int tid = threadIdx.x;
  const int b0 = blockIdx.x * GB;
  const int l = tid & 63, w = tid >> 6;
  const int lr = l & 15, lg = l >> 4;
  #pragma unroll
  for (int i = tid; i < 6144; i += 512){
    const int row = i >> 4;
    const int ch  = (((i & 15)*16) ^ ((row & 7) << 4)) >> 4;
    GLDS16(&whh_b[(size_t)row*128 + ch*8], (char*)WL + (size_t)(i - l)*16);
  }
  const int ab = tid >> 5, ad = (tid & 31) * 4;
  float bi0a[4], bi1a[4], bi2a[4], bh0a[4], bh1a[4], bh2a[4], wfa[4];
  #pragma unroll
  for (int j=0;j<4;j++){
    bi0a[j]=bih[ad+j]; bi1a[j]=bih[128+ad+j]; bi2a[j]=bih[256+ad+j];
    bh0a[j]=bhh[ad+j]; bh1a[j]=bhh[128+ad+j]; bh2a[j]=bhh[256+ad+j];
    wfa[j]=Wfc[ad+j];
  }
  const float bfc0 = bfc[0];
  for (int i = tid; i < 16*64; i += 512){
    const int bb = i >> 6, j = i & 63;
    const float h0 = ctx[(size_t)(b0+bb)*128 + 2*j];
    const float h1 = ctx[(size_t)(b0+bb)*128 + 2*j + 1];
    hb2[bb*68 + j] = (uint)f2b(h0) | (((uint)f2b(h1)) << 16);
  }
  for (int step=0; step<32; step++){
    __syncthreads();   // WL (first iter) + hb2 + red visible
    if (step && tid < GB){
      const float dv = red[tid] + bfc0;
      deltas[(size_t)(b0+tid)*32 + (step-1)] = fmaxf(dv,0.f) + log1pf(__expf(-fabsf(dv)));
    }
    union { short8 v; uint4 q; } af[4];
    #pragma unroll
    for (int kc=0;kc<4;kc++)
      af[kc].q = *(const uint4*)&hb2[lr*68 + kc*16 + lg*4];
    f32x4 acc0 = {}, acc1 = {}, acc2 = {};
    #pragma unroll
    for (int kc=0;kc<4;kc++){
      const int sw = ((kc*32 + lg*8)*2);
      const int r0 = 16*w + lr, r1 = r0 + 128, r2 = r0 + 256;
      short8 wb0 = *(const short8*)((const char*)WL + ((r0*256 + sw) ^ ((r0&7)<<4)));
      short8 wb1 = *(const short8*)((const char*)WL + ((r1*256 + sw) ^ ((r1&7)<<4)));
      short8 wb2 = *(const short8*)((const char*)WL + ((r2*256 + sw) ^ ((r2&7)<<4)));
      acc0 = __builtin_amdgcn_mfma_f32_16x16x32_bf16(af[kc].v, wb0, acc0, 0,0,0);
      acc1 = __builtin_amdgcn_mfma_f32_16x16x32_bf16(af[kc].v, wb1, acc1, 0,0,0);
      acc2 = __builtin_amdgcn_mfma_f32_16x16x32_bf16(af[kc].v, wb2, acc2, 0,0,0);
    }
    #pragma unroll
    for (int r=0;r<4;r++){
      ghs[(lg*4+r)*388 + 16*w + lr]       = acc0[r];
      ghs[(lg*4+r)*388 + 16*w + 128 + lr] = acc1[r];
      ghs[(lg*4+r)*388 + 16*w + 256 + lr] = acc2[r];
    }
    __syncthreads();
    float4 gr = *(const float4*)&ghs[ab*388 + ad];
    float4 gz = *(const float4*)&ghs[ab*388 + 128 + ad];
    float4 gn = *(const float4*)&ghs[ab*388 + 256 + ad];
    const float grs[4] = {gr.x,gr.y,gr.z,gr.w};
    const float gzs[4] = {gz.x,gz.y,gz.z,gz.w};
    const float gns[4] = {gn.x,gn.y,gn.z,gn.w};
    const uint hp0 = hb2[ab*68 + (ad>>1)], hp1 = hb2[ab*68 + (ad>>1) + 1];
    const float h[4] = { b2f((ushort)hp0), b2f((ushort)(hp0>>16)),
                         b2f((ushort)hp1), b2f((ushort)(hp1>>16)) };
    float hn[4], pv = 0.f;
    #pragma unroll
    for (int j=0;j<4;j++){
      const float rr = 1.f/(1.f + __expf(-(bi0a[j] + bh0a[j] + grs[j])));
      const float zz = 1.f/(1.f + __expf(-(bi1a[j] + bh1a[j] + gzs[j])));
      const float nn = tanhf(bi2a[j] + rr*(gns[j] + bh2a[j]));
      hn[j] = (1.f - zz)*nn + zz*h[j];
      pv += hn[j]*wfa[j];
    }
    hb2[ab*68 + (ad>>1)]     = (uint)f2b(hn[0]) | (((uint)f2b(hn[1])) << 16);
    hb2[ab*68 + (ad>>1) + 1] = (uint)f2b(hn[2]) | (((uint)f2b(hn[3])) << 16);
    #pragma unroll
    for (int off=1; off<32; off<<=1) pv += __shfl_xor(pv, off, 64);
    if ((tid & 31) == 0) red[ab] = pv;
  }
  __syncthreads();
  if (tid < GB){
    const float dv = red[tid] + bfc0;
    deltas[(size_t)(b0+tid)*32 + 31] = fmaxf(dv,0.f) + log1pf(__expf(-fabsf(dv)));
  }
}

// ---------------- times construction + KL ----------------
__global__ __launch_bounds__(64) void k_final(
    const float* __restrict__ deltas, const int* __restrict__ num_pred,
    float* __restrict__ out)
{
  const int b = blockIdx.x, l = threadIdx.x;
  float d = (l < 32) ? deltas[b*32 + l] : 0.f;
  float c = d;
  #pragma unroll
  for (int off=1; off<32; off<<=1){
    float t = __shfl_up(c, off, 64);
    if (l >= off) c += t;
  }
  const int np = num_pred[b];
  float last = __shfl(c, np-1, 64);
  float denom = last + 1e-6f;
  float cjm = __shfl(c, (l==0 ? 0 : l-1), 64);
  float val = 0.f;
  if (l >= 1 && l <= 32 && (l-1) < np) val = cjm / denom;
  if (l == np + 1) val += 1.f;
  if (l < 34) out[(size_t)b*419 + l] = val;
  float ta = 0.f, tb = 0.f, tc = 0.f;
  for (int z = l; z < 128; z += 64){
    float ga = out[(size_t)b*419 + 162 + z];
    float tu = fmaxf(out[(size_t)b*419 + 290 + z], 1e-35f);
    ta += tu*tu; tb += ga*ga; tc += -2.f*logf(tu);
  }
  float v = ta + tb + tc;
  #pragma unroll
  for (int off=1; off<64; off<<=1) v += __shfl_xor(v, off, 64);
  if (l == 0) out[(size_t)b*419 + 418] = 0.5f*(v - 128.f);
}

extern "C" void kernel_launch(void* const* d_in, const int* in_sizes, int n_in,
                              void* d_out, int out_size, void* d_ws, size_t ws_size,
                              hipStream_t stream)
{
  (void)in_sizes; (void)n_in; (void)out_size; (void)ws_size;
  const float* d_t    = (const float*)d_in[0];
  const float* d_l    = (const float*)d_in[1];
  const int*   d_emb  = (const int*)  d_in[2];
  const int*   numprd = (const int*)  d_in[4];
  const float* poi    = (const float*)d_in[5];
  const float* W_time = (const float*)d_in[6];
  const float* W_space= (const float*)d_in[7];
  const float* agg    = (const float*)d_in[8];
  const float* Wqkv   = (const float*)d_in[9];
  const float* bqkv   = (const float*)d_in[10];
  const float* Wo     = (const float*)d_in[11];
  const float* bo     = (const float*)d_in[12];
  const float* ln1g   = (const float*)d_in[13];
  const float* ln1b   = (const float*)d_in[14];
  const float* W1     = (const float*)d_in[15];
  const float* b1     = (const float*)d_in[16];
  const float* W2     = (const float*)d_in[17];
  const float* b2     = (const float*)d_in[18];
  const float* ln2g   = (const float*)d_in[19];
  const float* ln2b   = (const float*)d_in[20];
  const float* Wg     = (const float*)d_in[21];
  const float* bg     = (const float*)d_in[22];
  const float* Wt     = (const float*)d_in[23];
  const float* bt     = (const float*)d_in[24];
  const float* Whh    = (const float*)d_in[26];
  const float* bih    = (const float*)d_in[27];
  const float* bhh    = (const float*)d_in[28];
  const float* Wfc    = (const float*)d_in[29];
  const float* bfc    = (const float*)d_in[30];
  float* out = (float*)d_out;

  char* ws = (char*)d_ws;
  size_t off = 0;
  auto alloc = [&](size_t bytes){ size_t o = off; off += (bytes + 255) & ~(size_t)255; return o; };
  ushort* xb    = (ushort*)(ws + alloc((size_t)MM*128*2));
  ushort* qkv   = (ushort*)(ws + alloc((size_t)MM*384*2));
  ushort* aob   = (ushort*)(ws + alloc((size_t)MM*128*2));
  ushort* wqkvb = (ushort*)(ws + alloc((size_t)LL*384*128*2));
  ushort* wob   = (ushort*)(ws + alloc((size_t)LL*128*128*2));
  ushort* w1b   = (ushort*)(ws + alloc((size_t)LL*256*128*2));
  ushort* w2b   = (ushort*)(ws + alloc((size_t)LL*128*256*2));
  ushort* whhb  = (ushort*)(ws + alloc((size_t)384*128*2));
  float*  ctxws = (float*) (ws + alloc(128*128*4));
  float*  deltas= (float*) (ws + alloc(128*32*4));

  const int n0 = LL*384*128, n1 = LL*128*128, n2 = LL*256*128, n3 = LL*128*256, n4 = 384*128;
  k_f2b5<<<(n0+n1+n2+n3+n4+255)/256,256,0,stream>>>(Wqkv,wqkvb,n0, Wo,wob,n1, W1,w1b,n2, W2,w2b,n3, Whh,whhb,n4);
  k_embed<<<(MM*DD)/256,256,0,stream>>>(d_t, d_l, d_emb, poi, W_time, W_space, agg, xb);

  for (int li = 0; li < LL; li++){
    k_gemm2<false><<<MM/128,512,0,stream>>>(xb, wqkvb + li*384*128, bqkv + li*384, qkv, 384);
    k_attn<<<BB*HH,512,0,stream>>>(qkv, aob);
    k_gemm_ln<<<MM/128,512,0,stream>>>(aob, wob + li*128*128, bo + li*128, xb,
                                       ln1g + li*128, ln1b + li*128, 128);
    k_ffn<<<MM/128,512,0,stream>>>(xb, w1b + li*256*128, b1 + li*256,
                                   w2b + li*128*256, b2 + li*128, xb,
                                   ln2g + li*128, ln2b + li*128);
  }

  k_ctx<<<128,256,0,stream>>>(xb, Wg, bg, Wt, bt, out, ctxws);
  k_gru<<<8,512,0,stream>>>(ctxws, whhb, bih, bhh, Wfc, bfc, deltas);
  k_final<<<128,64,0,stream>>>(deltas, numprd, out);
}

// Round 20
// 490.866 us; speedup vs baseline: 1.0363x; 1.0363x over previous
//
#include <hip/hip_runtime.h>

#define BB 128
#define SS 512
#define TT 513
#define DD 128
#define HH 4
#define LL 4
#define MM (BB*TT)   // 65664

typedef __attribute__((ext_vector_type(4))) float f32x4;
typedef __attribute__((ext_vector_type(16))) float f32x16;
typedef __attribute__((ext_vector_type(8))) short short8;

typedef const __attribute__((address_space(1))) char* gas_t;
typedef __attribute__((address_space(3))) char* las_t;
#define GLDS16(g, l) __builtin_amdgcn_global_load_lds((gas_t)(g), (las_t)(l), 16, 0, 0)

__device__ __forceinline__ float b2f(ushort u){
  union { uint i; float f; } c; c.i = ((uint)u) << 16; return c.f;
}
__device__ __forceinline__ ushort f2b(float f){
  union { float f; uint i; } c; c.f = f;
  uint x = c.i;
  return (ushort)((x + 0x7fffu + ((x >> 16) & 1u)) >> 16);
}
union S8 { short8 v; ushort u[8]; };

__device__ __forceinline__ uint cvtpk(float lo, float hi){
  uint r;
  asm("v_cvt_pk_bf16_f32 %0, %1, %2" : "=v"(r) : "v"(lo), "v"(hi));
  return r;
}
__device__ __forceinline__ float fexp2(float x){
#if __has_builtin(__builtin_amdgcn_exp2f)
  return __builtin_amdgcn_exp2f(x);
#else
  return exp2f(x);
#endif
}

// ---------------- embed ----------------
__global__ __launch_bounds__(256) void k_embed(
    const float* __restrict__ d_t, const float* __restrict__ d_l, const int* __restrict__ d_emb,
    const float* __restrict__ poi, const float* __restrict__ W_time, const float* __restrict__ W_space,
    const float* __restrict__ agg, ushort* __restrict__ xb)
{
  int gid = blockIdx.x*256 + threadIdx.x;
  if (gid >= MM*DD) return;
  int d = gid & 127;
  int m = gid >> 7;
  int b = m / TT, t = m % TT;
  float v;
  if (t == SS) v = agg[d];
  else {
    int bs = b*SS + t;
    v = d_t[bs]*W_time[d] + d_l[bs*2]*W_space[d*2] + d_l[bs*2+1]*W_space[d*2+1]
        + poi[(size_t)d_emb[bs]*DD + d];
  }
  xb[gid] = f2b(v);
}

// ---------------- fused f32 -> bf16 convert ----------------
__global__ __launch_bounds__(256) void k_f2b5(
    const float* __restrict__ s0, ushort* __restrict__ o0, int n0,
    const float* __restrict__ s1, ushort* __restrict__ o1, int n1,
    const float* __restrict__ s2, ushort* __restrict__ o2, int n2,
    const float* __restrict__ s3, ushort* __restrict__ o3, int n3,
    const float* __restrict__ s4, ushort* __restrict__ o4, int n4)
{
  int i = blockIdx.x*256 + threadIdx.x;
  if (i < n0){ o0[i] = f2b(s0[i]); return; } i -= n0;
  if (i < n1){ o1[i] = f2b(s1[i]); return; } i -= n1;
  if (i < n2){ o2[i] = f2b(s2[i]); return; } i -= n2;
  if (i < n3){ o3[i] = f2b(s3[i]); return; } i -= n3;
  if (i < n4){ o4[i] = f2b(s4[i]); }
}

// ---------------- GEMM v5 (K=128): 128-row tile, double-buffered W prefetch (qkv) ----------
template<bool RELU>
__global__ __launch_bounds__(512) void k_gemm2(
  const ushort* __restrict__ A, const ushort* __restrict__ W,
  const float* __restrict__ bias, ushort* __restrict__ Cout, const int N)
{
  __shared__ __align__(16) ushort As[128*128], Ws[2][64*128];
  const int tid = threadIdx.x;
  const int m0 = blockIdx.x * 128;
  const int l = tid & 63, wid = tid >> 6;
  const int wr = wid >> 1, wc = wid & 1;
  const int lr = l & 15, lg = l >> 4;
  #pragma unroll
  for (int i = tid; i < 2048; i += 512){
    const int row = i >> 4;
    const int ch  = (((i & 15)*16) ^ ((row & 7) << 4)) >> 4;
    GLDS16(&A[(size_t)(m0+row)*128 + ch*8], (char*)As + (size_t)(i - l)*16);
  }
  #pragma unroll
  for (int i = tid; i < 1024; i += 512){
    const int row = i >> 4;
    const int ch  = (((i & 15)*16) ^ ((row & 7) << 4)) >> 4;
    GLDS16(&W[(size_t)row*128 + ch*8], (char*)Ws[0] + (size_t)(i - l)*16);
  }
  __syncthreads();
  int buf = 0;
  for (int n0 = 0; n0 < N; n0 += 64){
    if (n0 + 64 < N){
      #pragma unroll
      for (int i = tid; i < 1024; i += 512){
        const int row = i >> 4;
        const int ch  = (((i & 15)*16) ^ ((row & 7) << 4)) >> 4;
        GLDS16(&W[(size_t)(n0+64+row)*128 + ch*8], (char*)Ws[buf^1] + (size_t)(i - l)*16);
      }
    }
    f32x4 acc[2][2] = {};
    #pragma unroll
    for (int k0 = 0; k0 < 128; k0 += 32){
      const int sw = ((k0 + lg*8)*2) ^ ((lr & 7) << 4);
      short8 a0 = *(const short8*)((const char*)As + (wr*32+lr)*256 + sw);
      short8 a1 = *(const short8*)((const char*)As + (wr*32+16+lr)*256 + sw);
      short8 b0 = *(const short8*)((const char*)Ws[buf] + (wc*32+lr)*256 + sw);
      short8 b1 = *(const short8*)((const char*)Ws[buf] + (wc*32+16+lr)*256 + sw);
      acc[0][0] = __builtin_amdgcn_mfma_f32_16x16x32_bf16(a0, b0, acc[0][0], 0,0,0);
      acc[0][1] = __builtin_amdgcn_mfma_f32_16x16x32_bf16(a0, b1, acc[0][1], 0,0,0);
      acc[1][0] = __builtin_amdgcn_mfma_f32_16x16x32_bf16(a1, b0, acc[1][0], 0,0,0);
      acc[1][1] = __builtin_amdgcn_mfma_f32_16x16x32_bf16(a1, b1, acc[1][1], 0,0,0);
    }
    #pragma unroll
    for (int i=0;i<2;i++)
    #pragma unroll
    for (int j=0;j<2;j++)
    #pragma unroll
    for (int r=0;r<4;r++){
      const int lm = wr*32 + i*16 + lg*4 + r;
      const int ln = n0 + wc*32 + j*16 + lr;
      float v = acc[i][j][r] + bias[ln];
      if (RELU) v = fmaxf(v, 0.f);
      Cout[(size_t)(m0+lm)*N + ln] = f2b(v);
    }
    __syncthreads();   // drains prefetch vmcnt; protects Ws[buf] reuse
    buf ^= 1;
  }
}

// ---------------- fused GEMM (N=128, K=128) + residual(bf16) + LayerNorm (o-proj) ----------
__global__ __launch_bounds__(512) void k_gemm_ln(
  const ushort* __restrict__ A, const ushort* __restrict__ W,
  const float* __restrict__ bias, ushort* __restrict__ xb,
  const float* __restrict__ g, const float* __restrict__ bb, const int K)
{
  __shared__ __align__(16) ushort As[128*128], Ws[128*128];
  const int tid = threadIdx.x;
  const int m0 = blockIdx.x * 128;
  const int l = tid & 63, w = tid >> 6;
  const int lr = l & 15, lg = l >> 4;
  f32x4 acc[8] = {};
  for (int kt = 0; kt < K; kt += 128){
    if (kt) __syncthreads();
    #pragma unroll
    for (int i = tid; i < 2048; i += 512){
      const int row = i >> 4;
      const int ch  = (((i & 15)*16) ^ ((row & 7) << 4)) >> 4;
      GLDS16(&A[(size_t)(m0+row)*K + kt + ch*8], (char*)As + (size_t)(i - l)*16);
    }
    #pragma unroll
    for (int i = tid; i < 2048; i += 512){
      const int row = i >> 4;
      const int ch  = (((i & 15)*16) ^ ((row & 7) << 4)) >> 4;
      GLDS16(&W[(size_t)row*K + kt + ch*8], (char*)Ws + (size_t)(i - l)*16);
    }
    __syncthreads();
    #pragma unroll
    for (int k0 = 0; k0 < 128; k0 += 32){
      const int sw = ((k0 + lg*8)*2) ^ ((lr & 7) << 4);
      short8 a = *(const short8*)((const char*)As + (w*16+lr)*256 + sw);
      #pragma unroll
      for (int j=0;j<8;j++){
        short8 bf = *(const short8*)((const char*)Ws + (j*16+lr)*256 + sw);
        acc[j] = __builtin_amdgcn_mfma_f32_16x16x32_bf16(a, bf, acc[j], 0,0,0);
      }
    }
  }
  float biasj[8], gj[8], bj[8];
  #pragma unroll
  for (int j=0;j<8;j++){ biasj[j]=bias[j*16+lr]; gj[j]=g[j*16+lr]; bj[j]=bb[j*16+lr]; }
  #pragma unroll
  for (int r=0;r<4;r++){
    const size_t row = (size_t)(m0 + w*16 + lg*4 + r);
    float resid[8], s=0.f, sq=0.f;
    #pragma unroll
    for (int j=0;j<8;j++){
      float v = acc[j][r] + biasj[j];
      resid[j] = b2f(xb[row*128 + j*16 + lr]) + v;
      s += resid[j]; sq += resid[j]*resid[j];
    }
    #pragma unroll
    for (int off=1; off<16; off<<=1){ s += __shfl_xor(s,off,64); sq += __shfl_xor(sq,off,64); }
    const float mean = s*(1.f/128.f);
    const float var  = fmaxf(sq*(1.f/128.f) - mean*mean, 0.f);
    const float rstd = rsqrtf(var + 1e-5f);
    #pragma unroll
    for (int j=0;j<8;j++){
      float o = (resid[j]-mean)*rstd*gj[j] + bj[j];
      xb[row*128 + j*16 + lr] = f2b(o);
    }
  }
}

// ---------------- fused FFN ----------------
__global__ __launch_bounds__(512) void k_ffn(
  const ushort* __restrict__ A, const ushort* __restrict__ W1, const float* __restrict__ b1,
  const ushort* __restrict__ W2, const float* __restrict__ b2,
  ushort* __restrict__ xb, const float* __restrict__ g, const float* __restrict__ bb)
{
  __shared__ __align__(16) ushort As[128*128];   // 32 KB
  __shared__ __align__(16) ushort W1s[64*128];   // 16 KB
  __shared__ __align__(16) ushort W2s[128*64];   // 16 KB
  __shared__ __align__(16) ushort Hs[128*64];    // 16 KB
  const int tid = threadIdx.x;
  const int m0 = blockIdx.x * 128;
  const int l = tid & 63, w = tid >> 6;
  const int lr = l & 15, lg = l >> 4;
  #pragma unroll
  for (int i = tid; i < 2048; i += 512){
    const int row = i >> 4;
    const int ch  = (((i & 15)*16) ^ ((row & 7) << 4)) >> 4;
    GLDS16(&A[(size_t)(m0+row)*128 + ch*8], (char*)As + (size_t)(i - l)*16);
  }
  f32x4 acc2[8] = {};
  for (int c = 0; c < 4; c++){
    __syncthreads();
    #pragma unroll
    for (int i = tid; i < 1024; i += 512){
      const int row = i >> 4;
      const int ch  = (((i & 15)*16) ^ ((row & 7) << 4)) >> 4;
      GLDS16(&W1[(size_t)(c*64+row)*128 + ch*8], (char*)W1s + (size_t)(i - l)*16);
    }
    #pragma unroll
    for (int i = tid; i < 1024; i += 512){
      const int row = i >> 3;
      const int ch  = (i & 7) ^ (row & 7);
      GLDS16(&W2[(size_t)row*256 + c*64 + ch*8], (char*)W2s + (size_t)(i - l)*16);
    }
    __syncthreads();
    f32x4 acc1[4] = {};
    #pragma unroll
    for (int k0 = 0; k0 < 128; k0 += 32){
      const int sw = ((k0 + lg*8)*2) ^ ((lr & 7) << 4);
      short8 a = *(const short8*)((const char*)As + (w*16+lr)*256 + sw);
      #pragma unroll
      for (int j=0;j<4;j++){
        short8 bf = *(const short8*)((const char*)W1s + (j*16+lr)*256 + sw);
        acc1[j] = __builtin_amdgcn_mfma_f32_16x16x32_bf16(a, bf, acc1[j], 0,0,0);
      }
    }
    #pragma unroll
    for (int j=0;j<4;j++){
      const float b1j = b1[c*64 + j*16 + lr];
      #pragma unroll
      for (int r=0;r<4;r++){
        const int row = w*16 + lg*4 + r;
        const int col = j*16 + lr;
        const float v = fmaxf(acc1[j][r] + b1j, 0.f);
        *(ushort*)((char*)Hs + ((row*128 + col*2) ^ ((row & 7) << 4))) = f2b(v);
      }
    }
    __syncthreads();
    #pragma unroll
    for (int kk=0; kk<2; kk++){
      const int sw2 = (kk*32 + lg*8)*2;
      short8 ha = *(const short8*)((const char*)Hs + (((w*16+lr)*128 + sw2) ^ ((lr & 7) << 4)));
      #pragma unroll
      for (int j=0;j<8;j++){
        short8 wf = *(const short8*)((const char*)W2s + (((j*16+lr)*128 + sw2) ^ ((lr & 7) << 4)));
        acc2[j] = __builtin_amdgcn_mfma_f32_16x16x32_bf16(ha, wf, acc2[j], 0,0,0);
      }
    }
  }
  float biasj[8], gj[8], bj[8];
  #pragma unroll
  for (int j=0;j<8;j++){ biasj[j]=b2[j*16+lr]; gj[j]=g[j*16+lr]; bj[j]=bb[j*16+lr]; }
  #pragma unroll
  for (int r=0;r<4;r++){
    const int rl = w*16 + lg*4 + r;
    const size_t row = (size_t)(m0 + rl);
    float resid[8], s=0.f, sq=0.f;
    #pragma unroll
    for (int j=0;j<8;j++){
      const float v = acc2[j][r] + biasj[j];
      const ushort xu = *(const ushort*)((const char*)As + ((rl*256 + (j*16+lr)*2) ^ ((rl & 7) << 4)));
      resid[j] = b2f(xu) + v;
      s += resid[j]; sq += resid[j]*resid[j];
    }
    #pragma unroll
    for (int off=1; off<16; off<<=1){ s += __shfl_xor(s,off,64); sq += __shfl_xor(sq,off,64); }
    const float mean = s*(1.f/128.f);
    const float var  = fmaxf(sq*(1.f/128.f) - mean*mean, 0.f);
    const float rstd = rsqrtf(var + 1e-5f);
    #pragma unroll
    for (int j=0;j<8;j++){
      const float o = (resid[j]-mean)*rstd*gj[j] + bj[j];
      xb[row*128 + j*16 + lr] = f2b(o);
    }
  }
}

// ---------------- flash attention v5b (no setprio) ----------------
#define VSTRIDE 544
#define NEGM 30000.f
#define MFMA32(a,b,c) __builtin_amdgcn_mfma_f32_32x32x16_bf16(a,b,c,0,0,0)

__global__ __launch_bounds__(512) void k_attn(const ushort* __restrict__ qkv, ushort* __restrict__ ao)
{
  __shared__ __align__(16) ushort KL[VSTRIDE*32];
  __shared__ __align__(16) ushort VT[32*VSTRIDE];
  const int tid = threadIdx.x;
  const int b = blockIdx.x >> 2, h = blockIdx.x & 3;
  const size_t base = (size_t)b*TT*384 + h*32;
  union { short4 v; ushort u[4]; } sv;
  for (int i = tid; i < 8*VSTRIDE; i += 512){
    int t = i >> 3, dc = (i & 7)*4;
    sv.u[0]=0; sv.u[1]=0; sv.u[2]=0; sv.u[3]=0;
    if (t < TT) sv.v = *(const short4*)&qkv[base + (size_t)t*384 + 128 + dc];
    *(short4*)((char*)KL + ((t*64 + dc*2) ^ ((t&7)<<4))) = sv.v;
  }
  for (int i = tid; i < 8*VSTRIDE; i += 512){
    int t = i >> 3, dc = (i & 7)*4;
    sv.u[0]=0; sv.u[1]=0; sv.u[2]=0; sv.u[3]=0;
    if (t < TT) sv.v = *(const short4*)&qkv[base + (size_t)t*384 + 256 + dc];
    #pragma unroll
    for (int e=0;e<4;e++){
      int d = dc + e;
      *(ushort*)((char*)VT + ((d*1088 + t*2) ^ ((d&7)<<4))) = sv.u[e];
    }
  }
  __syncthreads();
  const int l = tid & 63, w = tid >> 6;
  const int lq = l & 31, hi = l >> 5;
  const float qscale = 0.25503486341f;
  const int krow = (lq & 3) | ((lq & 4) << 1) | ((lq & 8) >> 1) | (lq & 16);
  f32x16 cinit;
  #pragma unroll
  for (int r=0;r<16;r++) cinit[r] = -40.f;

  for (int qi = 0; qi < 3; qi++){
    const int qb = w + qi*8;
    if (qb >= 17) break;
    const int q0 = qb*32;
    int qrow = q0 + lq; if (qrow > SS) qrow = SS;
    S8 qa, qf0, qf1;
    qa.v = *(const short8*)&qkv[base + (size_t)qrow*384 + hi*8];
    #pragma unroll
    for (int j=0;j<8;j++) qf0.u[j] = f2b(b2f(qa.u[j]) * qscale);
    qa.v = *(const short8*)&qkv[base + (size_t)qrow*384 + 16 + hi*8];
    #pragma unroll
    for (int j=0;j<8;j++) qf1.u[j] = f2b(b2f(qa.u[j]) * qscale);

    float rsl = 0.f;
    f32x16 acc = {};
    int t0 = 0;
    for (int kb = 0; kb < 17; kb++, t0 += 32){
      const int trow = t0 + krow;
      short8 kc0 = *(const short8*)((const char*)KL + ((trow*64 + hi*16)      ^ ((trow&7)<<4)));
      short8 kc1 = *(const short8*)((const char*)KL + ((trow*64 + 32 + hi*16) ^ ((trow&7)<<4)));
      f32x16 s = MFMA32(kc0, qf0.v, cinit);
      s = MFMA32(kc1, qf1.v, s);
      if (t0 + 32 > TT){
        #pragma unroll
        for (int r=0;r<16;r++){
          const int key = t0 + (r&7) + 8*hi + 16*(r>>3);
          if (key >= TT) s[r] = -NEGM;
        }
      }
      float p[16];
      #pragma unroll
      for (int r=0;r<16;r++){ p[r] = fexp2(s[r]); rsl += p[r]; }
      union { short8 v; uint u[4]; } pa0, pa1;
      #pragma unroll
      for (int wd=0; wd<4; wd++){
        pa0.u[wd] = cvtpk(p[2*wd],   p[2*wd+1]);
        pa1.u[wd] = cvtpk(p[8+2*wd], p[8+2*wd+1]);
      }
      short8 v0 = *(const short8*)((const char*)VT + (((lq*1088) + (t0 + hi*8)*2)      ^ ((lq&7)<<4)));
      short8 v1 = *(const short8*)((const char*)VT + (((lq*1088) + (t0 + 16 + hi*8)*2) ^ ((lq&7)<<4)));
      acc = MFMA32(v0, pa0.v, acc);
      acc = MFMA32(v1, pa1.v, acc);
    }
    rsl += __shfl_xor(rsl, 32, 64);
    if (q0 + lq < TT){
      const float inv = 1.f / rsl;
      ushort* orow = ao + ((size_t)(b*TT + q0 + lq))*DD + h*32;
      #pragma unroll
      for (int r=0;r<16;r++){
        const int d = (r&3) + 8*(r>>2) + 4*hi;
        orow[d] = f2b(acc[r]*inv);
      }
    }
  }
}

// ---------------- ctx extraction + gamma/tau heads ----------------
__global__ __launch_bounds__(256) void k_ctx(
    const ushort* __restrict__ xb, const float* __restrict__ Wg, const float* __restrict__ bg,
    const float* __restrict__ Wt, const float* __restrict__ bt,
    float* __restrict__ out, float* __restrict__ ctxws)
{
  __shared__ float cs[128];
  const int b = blockIdx.x, tid = threadIdx.x;
  const ushort* xr = &xb[((size_t)b*TT + SS)*128];
  if (tid < 128){
    float v = b2f(xr[tid]);
    cs[tid] = v;
    out[(size_t)b*419 + 34 + tid] = v;
    ctxws[b*128 + tid] = v;
  }
  __syncthreads();
  const int j = tid & 127;
  const float* Wrow = (tid < 128) ? &Wg[(size_t)j*128] : &Wt[(size_t)j*128];
  float acc = 0.f;
  #pragma unroll 8
  for (int d=0; d<128; d+=4){
    float4 wv = *(const float4*)&Wrow[d];
    acc += cs[d]*wv.x + cs[d+1]*wv.y + cs[d+2]*wv.z + cs[d+3]*wv.w;
  }
  if (tid < 128){
    out[(size_t)b*419 + 162 + j] = acc + bg[j];
  } else {
    float tv = acc + bt[j];
    float sp = fmaxf(tv, 0.f) + log1pf(__expf(-fabsf(tv)));
    out[(size_t)b*419 + 290 + j] = sp;
  }
}

// ---------------- GRU decoder v7: MFMA-batched (16 batch/block, 8 waves) ----------------
#define GB 16
__global__ __launch_bounds__(512, 1) void k_gru(
    const float* __restrict__ ctx, const ushort* __restrict__ whh_b,
    const float* __restrict__ bih, const float* __restrict__ bhh,
    const float* __restrict__ Wfc, const float* __restrict__ bfc,
    float* __restrict__ deltas)
{
  __shared__ __align__(16) uint hb2[16*68];
  __shared__ __align__(16) float ghs[16*388];
  __shared__ float red[GB];
  const int tid = threadIdx.x;
  const int b0 = blockIdx.x * GB;
  const int l = tid & 63, w = tid >> 6;
  const int lr = l & 15, lg = l >> 4;
  short8 wb[3][4];
  #pragma unroll
  for (int t=0;t<3;t++){
    const int nrow = 16*w + t*128 + lr;
    #pragma unroll
    for (int kc=0;kc<4;kc++)
      wb[t][kc] = *(const short8*)&whh_b[(size_t)nrow*128 + kc*32 + lg*8];
  }
  const int ab = tid >> 5, ad = (tid & 31) * 4;
  float bi0a[4], bi1a[4], bi2a[4], bh0a[4], bh1a[4], bh2a[4], wfa[4];
  #pragma unroll
  for (int j=0;j<4;j++){
    bi0a[j]=bih[ad+j]; bi1a[j]=bih[128+ad+j]; bi2a[j]=bih[256+ad+j];
    bh0a[j]=bhh[ad+j]; bh1a[j]=bhh[128+ad+j]; bh2a[j]=bhh[256+ad+j];
    wfa[j]=Wfc[ad+j];
  }
  const float bfc0 = bfc[0];
  for (int i = tid; i < 16*64; i += 512){
    const int bb = i >> 6, j = i & 63;
    const float h0 = ctx[(size_t)(b0+bb)*128 + 2*j];
    const float h1 = ctx[(size_t)(b0+bb)*128 + 2*j + 1];
    hb2[bb*68 + j] = (uint)f2b(h0) | (((uint)f2b(h1)) << 16);
  }
  for (int step=0; step<32; step++){
    __syncthreads();
    if (step && tid < GB){
      const float dv = red[tid] + bfc0;
      deltas[(size_t)(b0+tid)*32 + (step-1)] = fmaxf(dv,0.f) + log1pf(__expf(-fabsf(dv)));
    }
    union { short8 v; uint4 q; } af[4];
    #pragma unroll
    for (int kc=0;kc<4;kc++)
      af[kc].q = *(const uint4*)&hb2[lr*68 + kc*16 + lg*4];
    f32x4 acc0 = {}, acc1 = {}, acc2 = {};
    #pragma unroll
    for (int kc=0;kc<4;kc++){
      acc0 = __builtin_amdgcn_mfma_f32_16x16x32_bf16(af[kc].v, wb[0][kc], acc0, 0,0,0);
      acc1 = __builtin_amdgcn_mfma_f32_16x16x32_bf16(af[kc].v, wb[1][kc], acc1, 0,0,0);
      acc2 = __builtin_amdgcn_mfma_f32_16x16x32_bf16(af[kc].v, wb[2][kc], acc2, 0,0,0);
    }
    #pragma unroll
    for (int r=0;r<4;r++){
      ghs[(lg*4+r)*388 + 16*w + lr]       = acc0[r];
      ghs[(lg*4+r)*388 + 16*w + 128 + lr] = acc1[r];
      ghs[(lg*4+r)*388 + 16*w + 256 + lr] = acc2[r];
    }
    __syncthreads();
    float4 gr = *(const float4*)&ghs[ab*388 + ad];
    float4 gz = *(const float4*)&ghs[ab*388 + 128 + ad];
    float4 gn = *(const float4*)&ghs[ab*388 + 256 + ad];
    const float grs[4] = {gr.x,gr.y,gr.z,gr.w};
    const float gzs[4] = {gz.x,gz.y,gz.z,gz.w};
    const float gns[4] = {gn.x,gn.y,gn.z,gn.w};
    const uint hp0 = hb2[ab*68 + (ad>>1)], hp1 = hb2[ab*68 + (ad>>1) + 1];
    const float h[4] = { b2f((ushort)hp0), b2f((ushort)(hp0>>16)),
                         b2f((ushort)hp1), b2f((ushort)(hp1>>16)) };
    float hn[4], pv = 0.f;
    #pragma unroll
    for (int j=0;j<4;j++){
      const float rr = 1.f/(1.f + __expf(-(bi0a[j] + bh0a[j] + grs[j])));
      const float zz = 1.f/(1.f + __expf(-(bi1a[j] + bh1a[j] + gzs[j])));
      const float nn = tanhf(bi2a[j] + rr*(gns[j] + bh2a[j]));
      hn[j] = (1.f - zz)*nn + zz*h[j];
      pv += hn[j]*wfa[j];
    }
    hb2[ab*68 + (ad>>1)]     = (uint)f2b(hn[0]) | (((uint)f2b(hn[1])) << 16);
    hb2[ab*68 + (ad>>1) + 1] = (uint)f2b(hn[2]) | (((uint)f2b(hn[3])) << 16);
    #pragma unroll
    for (int off=1; off<32; off<<=1) pv += __shfl_xor(pv, off, 64);
    if ((tid & 31) == 0) red[ab] = pv;
  }
  __syncthreads();
  if (tid < GB){
    const float dv = red[tid] + bfc0;
    deltas[(size_t)(b0+tid)*32 + 31] = fmaxf(dv,0.f) + log1pf(__expf(-fabsf(dv)));
  }
}

// ---------------- times construction + KL ----------------
__global__ __launch_bounds__(64) void k_final(
    const float* __restrict__ deltas, const int* __restrict__ num_pred,
    float* __restrict__ out)
{
  const int b = blockIdx.x, l = threadIdx.x;
  float d = (l < 32) ? deltas[b*32 + l] : 0.f;
  float c = d;
  #pragma unroll
  for (int off=1; off<32; off<<=1){
    float t = __shfl_up(c, off, 64);
    if (l >= off) c += t;
  }
  const int np = num_pred[b];
  float last = __shfl(c, np-1, 64);
  float denom = last + 1e-6f;
  float cjm = __shfl(c, (l==0 ? 0 : l-1), 64);
  float val = 0.f;
  if (l >= 1 && l <= 32 && (l-1) < np) val = cjm / denom;
  if (l == np + 1) val += 1.f;
  if (l < 34) out[(size_t)b*419 + l] = val;
  float ta = 0.f, tb = 0.f, tc = 0.f;
  for (int z = l; z < 128; z += 64){
    float ga = out[(size_t)b*419 + 162 + z];
    float tu = fmaxf(out[(size_t)b*419 + 290 + z], 1e-35f);
    ta += tu*tu; tb += ga*ga; tc += -2.f*logf(tu);
  }
  float v = ta + tb + tc;
  #pragma unroll
  for (int off=1; off<64; off<<=1) v += __shfl_xor(v, off, 64);
  if (l == 0) out[(size_t)b*419 + 418] = 0.5f*(v - 128.f);
}

extern "C" void kernel_launch(void* const* d_in, const int* in_sizes, int n_in,
                              void* d_out, int out_size, void* d_ws, size_t ws_size,
                              hipStream_t stream)
{
  (void)in_sizes; (void)n_in; (void)out_size; (void)ws_size;
  const float* d_t    = (const float*)d_in[0];
  const float* d_l    = (const float*)d_in[1];
  const int*   d_emb  = (const int*)  d_in[2];
  const int*   numprd = (const int*)  d_in[4];
  const float* poi    = (const float*)d_in[5];
  const float* W_time = (const float*)d_in[6];
  const float* W_space= (const float*)d_in[7];
  const float* agg    = (const float*)d_in[8];
  const float* Wqkv   = (const float*)d_in[9];
  const float* bqkv   = (const float*)d_in[10];
  const float* Wo     = (const float*)d_in[11];
  const float* bo     = (const float*)d_in[12];
  const float* ln1g   = (const float*)d_in[13];
  const float* ln1b   = (const float*)d_in[14];
  const float* W1     = (const float*)d_in[15];
  const float* b1     = (const float*)d_in[16];
  const float* W2     = (const float*)d_in[17];
  const float* b2     = (const float*)d_in[18];
  const float* ln2g   = (const float*)d_in[19];
  const float* ln2b   = (const float*)d_in[20];
  const float* Wg     = (const float*)d_in[21];
  const float* bg     = (const float*)d_in[22];
  const float* Wt     = (const float*)d_in[23];
  const float* bt     = (const float*)d_in[24];
  const float* Whh    = (const float*)d_in[26];
  const float* bih    = (const float*)d_in[27];
  const float* bhh    = (const float*)d_in[28];
  const float* Wfc    = (const float*)d_in[29];
  const float* bfc    = (const float*)d_in[30];
  float* out = (float*)d_out;

  char* ws = (char*)d_ws;
  size_t off = 0;
  auto alloc = [&](size_t bytes){ size_t o = off; off += (bytes + 255) & ~(size_t)255; return o; };
  ushort* xb    = (ushort*)(ws + alloc((size_t)MM*128*2));
  ushort* qkv   = (ushort*)(ws + alloc((size_t)MM*384*2));
  ushort* aob   = (ushort*)(ws + alloc((size_t)MM*128*2));
  ushort* wqkvb = (ushort*)(ws + alloc((size_t)LL*384*128*2));
  ushort* wob   = (ushort*)(ws + alloc((size_t)LL*128*128*2));
  ushort* w1b   = (ushort*)(ws + alloc((size_t)LL*256*128*2));
  ushort* w2b   = (ushort*)(ws + alloc((size_t)LL*128*256*2));
  ushort* whhb  = (ushort*)(ws + alloc((size_t)384*128*2));
  float*  ctxws = (float*) (ws + alloc(128*128*4));
  float*  deltas= (float*) (ws + alloc(128*32*4));

  const int n0 = LL*384*128, n1 = LL*128*128, n2 = LL*256*128, n3 = LL*128*256, n4 = 384*128;
  k_f2b5<<<(n0+n1+n2+n3+n4+255)/256,256,0,stream>>>(Wqkv,wqkvb,n0, Wo,wob,n1, W1,w1b,n2, W2,w2b,n3, Whh,whhb,n4);
  k_embed<<<(MM*DD)/256,256,0,stream>>>(d_t, d_l, d_emb, poi, W_time, W_space, agg, xb);

  for (int li = 0; li < LL; li++){
    k_gemm2<false><<<MM/128,512,0,stream>>>(xb, wqkvb + li*384*128, bqkv + li*384, qkv, 384);
    k_attn<<<BB*HH,512,0,stream>>>(qkv, aob);
    k_gemm_ln<<<MM/128,512,0,stream>>>(aob, wob + li*128*128, bo + li*128, xb,
                                       ln1g + li*128, ln1b + li*128, 128);
    k_ffn<<<MM/128,512,0,stream>>>(xb, w1b + li*256*128, b1 + li*256,
                                   w2b + li*128*256, b2 + li*128, xb,
                                   ln2g + li*128, ln2b + li*128);
  }

  k_ctx<<<128,256,0,stream>>>(xb, Wg, bg, Wt, bt, out, ctxws);
  k_gru<<<8,512,0,stream>>>(ctxws, whhb, bih, bhh, Wfc, bfc, deltas);
  k_final<<<128,64,0,stream>>>(deltas, numprd, out);
}

// Round 21
// 478.310 us; speedup vs baseline: 1.0635x; 1.0263x over previous
//
#include <hip/hip_runtime.h>

#define BB 128
#define SS 512
#define TT 513
#define DD 128
#define HH 4
#define LL 4
#define MM (BB*TT)   // 65664

typedef __attribute__((ext_vector_type(4))) float f32x4;
typedef __attribute__((ext_vector_type(16))) float f32x16;
typedef __attribute__((ext_vector_type(8))) short short8;

typedef const __attribute__((address_space(1))) char* gas_t;
typedef __attribute__((address_space(3))) char* las_t;
#define GLDS16(g, l) __builtin_amdgcn_global_load_lds((gas_t)(g), (las_t)(l), 16, 0, 0)

__device__ __forceinline__ float b2f(ushort u){
  union { uint i; float f; } c; c.i = ((uint)u) << 16; return c.f;
}
__device__ __forceinline__ ushort f2b(float f){
  union { float f; uint i; } c; c.f = f;
  uint x = c.i;
  return (ushort)((x + 0x7fffu + ((x >> 16) & 1u)) >> 16);
}
union S8 { short8 v; ushort u[8]; };

__device__ __forceinline__ uint cvtpk(float lo, float hi){
  uint r;
  asm("v_cvt_pk_bf16_f32 %0, %1, %2" : "=v"(r) : "v"(lo), "v"(hi));
  return r;
}
__device__ __forceinline__ float fexp2(float x){
#if __has_builtin(__builtin_amdgcn_exp2f)
  return __builtin_amdgcn_exp2f(x);
#else
  return exp2f(x);
#endif
}

// ---------------- embed ----------------
__global__ __launch_bounds__(256) void k_embed(
    const float* __restrict__ d_t, const float* __restrict__ d_l, const int* __restrict__ d_emb,
    const float* __restrict__ poi, const float* __restrict__ W_time, const float* __restrict__ W_space,
    const float* __restrict__ agg, ushort* __restrict__ xb)
{
  int gid = blockIdx.x*256 + threadIdx.x;
  if (gid >= MM*DD) return;
  int d = gid & 127;
  int m = gid >> 7;
  int b = m / TT, t = m % TT;
  float v;
  if (t == SS) v = agg[d];
  else {
    int bs = b*SS + t;
    v = d_t[bs]*W_time[d] + d_l[bs*2]*W_space[d*2] + d_l[bs*2+1]*W_space[d*2+1]
        + poi[(size_t)d_emb[bs]*DD + d];
  }
  xb[gid] = f2b(v);
}

// ---------------- fused f32 -> bf16 convert ----------------
__global__ __launch_bounds__(256) void k_f2b5(
    const float* __restrict__ s0, ushort* __restrict__ o0, int n0,
    const float* __restrict__ s1, ushort* __restrict__ o1, int n1,
    const float* __restrict__ s2, ushort* __restrict__ o2, int n2,
    const float* __restrict__ s3, ushort* __restrict__ o3, int n3,
    const float* __restrict__ s4, ushort* __restrict__ o4, int n4)
{
  int i = blockIdx.x*256 + threadIdx.x;
  if (i < n0){ o0[i] = f2b(s0[i]); return; } i -= n0;
  if (i < n1){ o1[i] = f2b(s1[i]); return; } i -= n1;
  if (i < n2){ o2[i] = f2b(s2[i]); return; } i -= n2;
  if (i < n3){ o3[i] = f2b(s3[i]); return; } i -= n3;
  if (i < n4){ o4[i] = f2b(s4[i]); }
}

// ---------------- GEMM v4 (K=128): 128-row M-tile, 512 threads, global_load_lds staging ------
template<bool RELU>
__global__ __launch_bounds__(512) void k_gemm2(
  const ushort* __restrict__ A, const ushort* __restrict__ W,
  const float* __restrict__ bias, ushort* __restrict__ Cout, const int N)
{
  __shared__ __align__(16) ushort As[128*128], Ws[64*128];
  const int tid = threadIdx.x;
  const int m0 = blockIdx.x * 128;
  const int l = tid & 63, wid = tid >> 6;
  const int wr = wid >> 1, wc = wid & 1;
  const int lr = l & 15, lg = l >> 4;
  #pragma unroll
  for (int i = tid; i < 2048; i += 512){
    const int row = i >> 4;
    const int ch  = (((i & 15)*16) ^ ((row & 7) << 4)) >> 4;
    GLDS16(&A[(size_t)(m0+row)*128 + ch*8], (char*)As + (size_t)(i - l)*16);
  }
  for (int n0 = 0; n0 < N; n0 += 64){
    if (n0) __syncthreads();
    #pragma unroll
    for (int i = tid; i < 1024; i += 512){
      const int row = i >> 4;
      const int ch  = (((i & 15)*16) ^ ((row & 7) << 4)) >> 4;
      GLDS16(&W[(size_t)(n0+row)*128 + ch*8], (char*)Ws + (size_t)(i - l)*16);
    }
    __syncthreads();
    f32x4 acc[2][2] = {};
    #pragma unroll
    for (int k0 = 0; k0 < 128; k0 += 32){
      const int sw = ((k0 + lg*8)*2) ^ ((lr & 7) << 4);
      short8 a0 = *(const short8*)((const char*)As + (wr*32+lr)*256 + sw);
      short8 a1 = *(const short8*)((const char*)As + (wr*32+16+lr)*256 + sw);
      short8 b0 = *(const short8*)((const char*)Ws + (wc*32+lr)*256 + sw);
      short8 b1 = *(const short8*)((const char*)Ws + (wc*32+16+lr)*256 + sw);
      acc[0][0] = __builtin_amdgcn_mfma_f32_16x16x32_bf16(a0, b0, acc[0][0], 0,0,0);
      acc[0][1] = __builtin_amdgcn_mfma_f32_16x16x32_bf16(a0, b1, acc[0][1], 0,0,0);
      acc[1][0] = __builtin_amdgcn_mfma_f32_16x16x32_bf16(a1, b0, acc[1][0], 0,0,0);
      acc[1][1] = __builtin_amdgcn_mfma_f32_16x16x32_bf16(a1, b1, acc[1][1], 0,0,0);
    }
    #pragma unroll
    for (int i=0;i<2;i++)
    #pragma unroll
    for (int j=0;j<2;j++)
    #pragma unroll
    for (int r=0;r<4;r++){
      const int lm = wr*32 + i*16 + lg*4 + r;
      const int ln = n0 + wc*32 + j*16 + lr;
      float v = acc[i][j][r] + bias[ln];
      if (RELU) v = fmaxf(v, 0.f);
      Cout[(size_t)(m0+lm)*N + ln] = f2b(v);
    }
  }
}

// ---------------- fused GEMM (N=128, K=128) + residual(bf16) + LayerNorm (o-proj) ----------
__global__ __launch_bounds__(512) void k_gemm_ln(
  const ushort* __restrict__ A, const ushort* __restrict__ W,
  const float* __restrict__ bias, ushort* __restrict__ xb,
  const float* __restrict__ g, const float* __restrict__ bb, const int K)
{
  __shared__ __align__(16) ushort As[128*128], Ws[128*128];
  const int tid = threadIdx.x;
  const int m0 = blockIdx.x * 128;
  const int l = tid & 63, w = tid >> 6;
  const int lr = l & 15, lg = l >> 4;
  f32x4 acc[8] = {};
  for (int kt = 0; kt < K; kt += 128){
    if (kt) __syncthreads();
    #pragma unroll
    for (int i = tid; i < 2048; i += 512){
      const int row = i >> 4;
      const int ch  = (((i & 15)*16) ^ ((row & 7) << 4)) >> 4;
      GLDS16(&A[(size_t)(m0+row)*K + kt + ch*8], (char*)As + (size_t)(i - l)*16);
    }
    #pragma unroll
    for (int i = tid; i < 2048; i += 512){
      const int row = i >> 4;
      const int ch  = (((i & 15)*16) ^ ((row & 7) << 4)) >> 4;
      GLDS16(&W[(size_t)row*K + kt + ch*8], (char*)Ws + (size_t)(i - l)*16);
    }
    __syncthreads();
    #pragma unroll
    for (int k0 = 0; k0 < 128; k0 += 32){
      const int sw = ((k0 + lg*8)*2) ^ ((lr & 7) << 4);
      short8 a = *(const short8*)((const char*)As + (w*16+lr)*256 + sw);
      #pragma unroll
      for (int j=0;j<8;j++){
        short8 bf = *(const short8*)((const char*)Ws + (j*16+lr)*256 + sw);
        acc[j] = __builtin_amdgcn_mfma_f32_16x16x32_bf16(a, bf, acc[j], 0,0,0);
      }
    }
  }
  float biasj[8], gj[8], bj[8];
  #pragma unroll
  for (int j=0;j<8;j++){ biasj[j]=bias[j*16+lr]; gj[j]=g[j*16+lr]; bj[j]=bb[j*16+lr]; }
  #pragma unroll
  for (int r=0;r<4;r++){
    const size_t row = (size_t)(m0 + w*16 + lg*4 + r);
    float resid[8], s=0.f, sq=0.f;
    #pragma unroll
    for (int j=0;j<8;j++){
      float v = acc[j][r] + biasj[j];
      resid[j] = b2f(xb[row*128 + j*16 + lr]) + v;
      s += resid[j]; sq += resid[j]*resid[j];
    }
    #pragma unroll
    for (int off=1; off<16; off<<=1){ s += __shfl_xor(s,off,64); sq += __shfl_xor(sq,off,64); }
    const float mean = s*(1.f/128.f);
    const float var  = fmaxf(sq*(1.f/128.f) - mean*mean, 0.f);
    const float rstd = rsqrtf(var + 1e-5f);
    #pragma unroll
    for (int j=0;j<8;j++){
      float o = (resid[j]-mean)*rstd*gj[j] + bj[j];
      xb[row*128 + j*16 + lr] = f2b(o);
    }
  }
}

// ---------------- fused FFN ----------------
__global__ __launch_bounds__(512) void k_ffn(
  const ushort* __restrict__ A, const ushort* __restrict__ W1, const float* __restrict__ b1,
  const ushort* __restrict__ W2, const float* __restrict__ b2,
  ushort* __restrict__ xb, const float* __restrict__ g, const float* __restrict__ bb)
{
  __shared__ __align__(16) ushort As[128*128];   // 32 KB
  __shared__ __align__(16) ushort W1s[64*128];   // 16 KB
  __shared__ __align__(16) ushort W2s[128*64];   // 16 KB
  __shared__ __align__(16) ushort Hs[128*64];    // 16 KB
  const int tid = threadIdx.x;
  const int m0 = blockIdx.x * 128;
  const int l = tid & 63, w = tid >> 6;
  const int lr = l & 15, lg = l >> 4;
  #pragma unroll
  for (int i = tid; i < 2048; i += 512){
    const int row = i >> 4;
    const int ch  = (((i & 15)*16) ^ ((row & 7) << 4)) >> 4;
    GLDS16(&A[(size_t)(m0+row)*128 + ch*8], (char*)As + (size_t)(i - l)*16);
  }
  f32x4 acc2[8] = {};
  for (int c = 0; c < 4; c++){
    __syncthreads();
    #pragma unroll
    for (int i = tid; i < 1024; i += 512){
      const int row = i >> 4;
      const int ch  = (((i & 15)*16) ^ ((row & 7) << 4)) >> 4;
      GLDS16(&W1[(size_t)(c*64+row)*128 + ch*8], (char*)W1s + (size_t)(i - l)*16);
    }
    #pragma unroll
    for (int i = tid; i < 1024; i += 512){
      const int row = i >> 3;
      const int ch  = (i & 7) ^ (row & 7);
      GLDS16(&W2[(size_t)row*256 + c*64 + ch*8], (char*)W2s + (size_t)(i - l)*16);
    }
    __syncthreads();
    f32x4 acc1[4] = {};
    #pragma unroll
    for (int k0 = 0; k0 < 128; k0 += 32){
      const int sw = ((k0 + lg*8)*2) ^ ((lr & 7) << 4);
      short8 a = *(const short8*)((const char*)As + (w*16+lr)*256 + sw);
      #pragma unroll
      for (int j=0;j<4;j++){
        short8 bf = *(const short8*)((const char*)W1s + (j*16+lr)*256 + sw);
        acc1[j] = __builtin_amdgcn_mfma_f32_16x16x32_bf16(a, bf, acc1[j], 0,0,0);
      }
    }
    #pragma unroll
    for (int j=0;j<4;j++){
      const float b1j = b1[c*64 + j*16 + lr];
      #pragma unroll
      for (int r=0;r<4;r++){
        const int row = w*16 + lg*4 + r;
        const int col = j*16 + lr;
        const float v = fmaxf(acc1[j][r] + b1j, 0.f);
        *(ushort*)((char*)Hs + ((row*128 + col*2) ^ ((row & 7) << 4))) = f2b(v);
      }
    }
    __syncthreads();
    #pragma unroll
    for (int kk=0; kk<2; kk++){
      const int sw2 = (kk*32 + lg*8)*2;
      short8 ha = *(const short8*)((const char*)Hs + (((w*16+lr)*128 + sw2) ^ ((lr & 7) << 4)));
      #pragma unroll
      for (int j=0;j<8;j++){
        short8 wf = *(const short8*)((const char*)W2s + (((j*16+lr)*128 + sw2) ^ ((lr & 7) << 4)));
        acc2[j] = __builtin_amdgcn_mfma_f32_16x16x32_bf16(ha, wf, acc2[j], 0,0,0);
      }
    }
  }
  float biasj[8], gj[8], bj[8];
  #pragma unroll
  for (int j=0;j<8;j++){ biasj[j]=b2[j*16+lr]; gj[j]=g[j*16+lr]; bj[j]=bb[j*16+lr]; }
  #pragma unroll
  for (int r=0;r<4;r++){
    const int rl = w*16 + lg*4 + r;
    const size_t row = (size_t)(m0 + rl);
    float resid[8], s=0.f, sq=0.f;
    #pragma unroll
    for (int j=0;j<8;j++){
      const float v = acc2[j][r] + biasj[j];
      const ushort xu = *(const ushort*)((const char*)As + ((rl*256 + (j*16+lr)*2) ^ ((rl & 7) << 4)));
      resid[j] = b2f(xu) + v;
      s += resid[j]; sq += resid[j]*resid[j];
    }
    #pragma unroll
    for (int off=1; off<16; off<<=1){ s += __shfl_xor(s,off,64); sq += __shfl_xor(sq,off,64); }
    const float mean = s*(1.f/128.f);
    const float var  = fmaxf(sq*(1.f/128.f) - mean*mean, 0.f);
    const float rstd = rsqrtf(var + 1e-5f);
    #pragma unroll
    for (int j=0;j<8;j++){
      const float o = (resid[j]-mean)*rstd*gj[j] + bj[j];
      xb[row*128 + j*16 + lr] = f2b(o);
    }
  }
}

// ---------------- flash attention v5b ----------------
#define VSTRIDE 544
#define NEGM 30000.f
#define MFMA32(a,b,c) __builtin_amdgcn_mfma_f32_32x32x16_bf16(a,b,c,0,0,0)

__global__ __launch_bounds__(512) void k_attn(const ushort* __restrict__ qkv, ushort* __restrict__ ao)
{
  __shared__ __align__(16) ushort KL[VSTRIDE*32];
  __shared__ __align__(16) ushort VT[32*VSTRIDE];
  const int tid = threadIdx.x;
  const int b = blockIdx.x >> 2, h = blockIdx.x & 3;
  const size_t base = (size_t)b*TT*384 + h*32;
  union { short4 v; ushort u[4]; } sv;
  for (int i = tid; i < 8*VSTRIDE; i += 512){
    int t = i >> 3, dc = (i & 7)*4;
    sv.u[0]=0; sv.u[1]=0; sv.u[2]=0; sv.u[3]=0;
    if (t < TT) sv.v = *(const short4*)&qkv[base + (size_t)t*384 + 128 + dc];
    *(short4*)((char*)KL + ((t*64 + dc*2) ^ ((t&7)<<4))) = sv.v;
  }
  for (int i = tid; i < 8*VSTRIDE; i += 512){
    int t = i >> 3, dc = (i & 7)*4;
    sv.u[0]=0; sv.u[1]=0; sv.u[2]=0; sv.u[3]=0;
    if (t < TT) sv.v = *(const short4*)&qkv[base + (size_t)t*384 + 256 + dc];
    #pragma unroll
    for (int e=0;e<4;e++){
      int d = dc + e;
      *(ushort*)((char*)VT + ((d*1088 + t*2) ^ ((d&7)<<4))) = sv.u[e];
    }
  }
  __syncthreads();
  const int l = tid & 63, w = tid >> 6;
  const int lq = l & 31, hi = l >> 5;
  const float qscale = 0.25503486341f;
  const int krow = (lq & 3) | ((lq & 4) << 1) | ((lq & 8) >> 1) | (lq & 16);
  f32x16 cinit;
  #pragma unroll
  for (int r=0;r<16;r++) cinit[r] = -40.f;

  for (int qi = 0; qi < 3; qi++){
    const int qb = w + qi*8;
    if (qb >= 17) break;
    const int q0 = qb*32;
    int qrow = q0 + lq; if (qrow > SS) qrow = SS;
    S8 qa, qf0, qf1;
    qa.v = *(const short8*)&qkv[base + (size_t)qrow*384 + hi*8];
    #pragma unroll
    for (int j=0;j<8;j++) qf0.u[j] = f2b(b2f(qa.u[j]) * qscale);
    qa.v = *(const short8*)&qkv[base + (size_t)qrow*384 + 16 + hi*8];
    #pragma unroll
    for (int j=0;j<8;j++) qf1.u[j] = f2b(b2f(qa.u[j]) * qscale);

    float rsl = 0.f;
    f32x16 acc = {};
    int t0 = 0;
    for (int kb = 0; kb < 17; kb++, t0 += 32){
      const int trow = t0 + krow;
      short8 kc0 = *(const short8*)((const char*)KL + ((trow*64 + hi*16)      ^ ((trow&7)<<4)));
      short8 kc1 = *(const short8*)((const char*)KL + ((trow*64 + 32 + hi*16) ^ ((trow&7)<<4)));
      f32x16 s = MFMA32(kc0, qf0.v, cinit);
      s = MFMA32(kc1, qf1.v, s);
      if (t0 + 32 > TT){
        #pragma unroll
        for (int r=0;r<16;r++){
          const int key = t0 + (r&7) + 8*hi + 16*(r>>3);
          if (key >= TT) s[r] = -NEGM;
        }
      }
      float p[16];
      #pragma unroll
      for (int r=0;r<16;r++){ p[r] = fexp2(s[r]); rsl += p[r]; }
      union { short8 v; uint u[4]; } pa0, pa1;
      #pragma unroll
      for (int wd=0; wd<4; wd++){
        pa0.u[wd] = cvtpk(p[2*wd],   p[2*wd+1]);
        pa1.u[wd] = cvtpk(p[8+2*wd], p[8+2*wd+1]);
      }
      short8 v0 = *(const short8*)((const char*)VT + (((lq*1088) + (t0 + hi*8)*2)      ^ ((lq&7)<<4)));
      short8 v1 = *(const short8*)((const char*)VT + (((lq*1088) + (t0 + 16 + hi*8)*2) ^ ((lq&7)<<4)));
      acc = MFMA32(v0, pa0.v, acc);
      acc = MFMA32(v1, pa1.v, acc);
    }
    rsl += __shfl_xor(rsl, 32, 64);
    if (q0 + lq < TT){
      const float inv = 1.f / rsl;
      ushort* orow = ao + ((size_t)(b*TT + q0 + lq))*DD + h*32;
      #pragma unroll
      for (int r=0;r<16;r++){
        const int d = (r&3) + 8*(r>>2) + 4*hi;
        orow[d] = f2b(acc[r]*inv);
      }
    }
  }
}

// ---------------- ctx extraction + gamma/tau heads ----------------
__global__ __launch_bounds__(256) void k_ctx(
    const ushort* __restrict__ xb, const float* __restrict__ Wg, const float* __restrict__ bg,
    const float* __restrict__ Wt, const float* __restrict__ bt,
    float* __restrict__ out, float* __restrict__ ctxws)
{
  __shared__ float cs[128];
  const int b = blockIdx.x, tid = threadIdx.x;
  const ushort* xr = &xb[((size_t)b*TT + SS)*128];
  if (tid < 128){
    float v = b2f(xr[tid]);
    cs[tid] = v;
    out[(size_t)b*419 + 34 + tid] = v;
    ctxws[b*128 + tid] = v;
  }
  __syncthreads();
  const int j = tid & 127;
  const float* Wrow = (tid < 128) ? &Wg[(size_t)j*128] : &Wt[(size_t)j*128];
  float acc = 0.f;
  #pragma unroll 8
  for (int d=0; d<128; d+=4){
    float4 wv = *(const float4*)&Wrow[d];
    acc += cs[d]*wv.x + cs[d+1]*wv.y + cs[d+2]*wv.z + cs[d+3]*wv.w;
  }
  if (tid < 128){
    out[(size_t)b*419 + 162 + j] = acc + bg[j];
  } else {
    float tv = acc + bt[j];
    float sp = fmaxf(tv, 0.f) + log1pf(__expf(-fabsf(tv)));
    out[(size_t)b*419 + 290 + j] = sp;
  }
}

// ---------------- GRU decoder v7: MFMA-batched (16 batch/block, 8 waves) ----------------
#define GB 16
__global__ __launch_bounds__(512, 1) void k_gru(
    const float* __restrict__ ctx, const ushort* __restrict__ whh_b,
    const float* __restrict__ bih, const float* __restrict__ bhh,
    const float* __restrict__ Wfc, const float* __restrict__ bfc,
    float* __restrict__ deltas)
{
  __shared__ __align__(16) uint hb2[16*68];
  __shared__ __align__(16) float ghs[16*388];
  __shared__ float red[GB];
  const int tid = threadIdx.x;
  const int b0 = blockIdx.x * GB;
  const int l = tid & 63, w = tid >> 6;
  const int lr = l & 15, lg = l >> 4;
  short8 wb[3][4];
  #pragma unroll
  for (int t=0;t<3;t++){
    const int nrow = 16*w + t*128 + lr;
    #pragma unroll
    for (int kc=0;kc<4;kc++)
      wb[t][kc] = *(const short8*)&whh_b[(size_t)nrow*128 + kc*32 + lg*8];
  }
  const int ab = tid >> 5, ad = (tid & 31) * 4;
  float bi0a[4], bi1a[4], bi2a[4], bh0a[4], bh1a[4], bh2a[4], wfa[4];
  #pragma unroll
  for (int j=0;j<4;j++){
    bi0a[j]=bih[ad+j]; bi1a[j]=bih[128+ad+j]; bi2a[j]=bih[256+ad+j];
    bh0a[j]=bhh[ad+j]; bh1a[j]=bhh[128+ad+j]; bh2a[j]=bhh[256+ad+j];
    wfa[j]=Wfc[ad+j];
  }
  const float bfc0 = bfc[0];
  for (int i = tid; i < 16*64; i += 512){
    const int bb = i >> 6, j = i & 63;
    const float h0 = ctx[(size_t)(b0+bb)*128 + 2*j];
    const float h1 = ctx[(size_t)(b0+bb)*128 + 2*j + 1];
    hb2[bb*68 + j] = (uint)f2b(h0) | (((uint)f2b(h1)) << 16);
  }
  for (int step=0; step<32; step++){
    __syncthreads();
    if (step && tid < GB){
      const float dv = red[tid] + bfc0;
      deltas[(size_t)(b0+tid)*32 + (step-1)] = fmaxf(dv,0.f) + log1pf(__expf(-fabsf(dv)));
    }
    union { short8 v; uint4 q; } af[4];
    #pragma unroll
    for (int kc=0;kc<4;kc++)
      af[kc].q = *(const uint4*)&hb2[lr*68 + kc*16 + lg*4];
    f32x4 acc0 = {}, acc1 = {}, acc2 = {};
    #pragma unroll
    for (int kc=0;kc<4;kc++){
      acc0 = __builtin_amdgcn_mfma_f32_16x16x32_bf16(af[kc].v, wb[0][kc], acc0, 0,0,0);
      acc1 = __builtin_amdgcn_mfma_f32_16x16x32_bf16(af[kc].v, wb[1][kc], acc1, 0,0,0);
      acc2 = __builtin_amdgcn_mfma_f32_16x16x32_bf16(af[kc].v, wb[2][kc], acc2, 0,0,0);
    }
    #pragma unroll
    for (int r=0;r<4;r++){
      ghs[(lg*4+r)*388 + 16*w + lr]       = acc0[r];
      ghs[(lg*4+r)*388 + 16*w + 128 + lr] = acc1[r];
      ghs[(lg*4+r)*388 + 16*w + 256 + lr] = acc2[r];
    }
    __syncthreads();
    float4 gr = *(const float4*)&ghs[ab*388 + ad];
    float4 gz = *(const float4*)&ghs[ab*388 + 128 + ad];
    float4 gn = *(const float4*)&ghs[ab*388 + 256 + ad];
    const float grs[4] = {gr.x,gr.y,gr.z,gr.w};
    const float gzs[4] = {gz.x,gz.y,gz.z,gz.w};
    const float gns[4] = {gn.x,gn.y,gn.z,gn.w};
    const uint hp0 = hb2[ab*68 + (ad>>1)], hp1 = hb2[ab*68 + (ad>>1) + 1];
    const float h[4] = { b2f((ushort)hp0), b2f((ushort)(hp0>>16)),
                         b2f((ushort)hp1), b2f((ushort)(hp1>>16)) };
    float hn[4], pv = 0.f;
    #pragma unroll
    for (int j=0;j<4;j++){
      const float rr = 1.f/(1.f + __expf(-(bi0a[j] + bh0a[j] + grs[j])));
      const float zz = 1.f/(1.f + __expf(-(bi1a[j] + bh1a[j] + gzs[j])));
      const float nn = tanhf(bi2a[j] + rr*(gns[j] + bh2a[j]));
      hn[j] = (1.f - zz)*nn + zz*h[j];
      pv += hn[j]*wfa[j];
    }
    hb2[ab*68 + (ad>>1)]     = (uint)f2b(hn[0]) | (((uint)f2b(hn[1])) << 16);
    hb2[ab*68 + (ad>>1) + 1] = (uint)f2b(hn[2]) | (((uint)f2b(hn[3])) << 16);
    #pragma unroll
    for (int off=1; off<32; off<<=1) pv += __shfl_xor(pv, off, 64);
    if ((tid & 31) == 0) red[ab] = pv;
  }
  __syncthreads();
  if (tid < GB){
    const float dv = red[tid] + bfc0;
    deltas[(size_t)(b0+tid)*32 + 31] = fmaxf(dv,0.f) + log1pf(__expf(-fabsf(dv)));
  }
}

// ---------------- times construction + KL ----------------
__global__ __launch_bounds__(64) void k_final(
    const float* __restrict__ deltas, const int* __restrict__ num_pred,
    float* __restrict__ out)
{
  const int b = blockIdx.x, l = threadIdx.x;
  float d = (l < 32) ? deltas[b*32 + l] : 0.f;
  float c = d;
  #pragma unroll
  for (int off=1; off<32; off<<=1){
    float t = __shfl_up(c, off, 64);
    if (l >= off) c += t;
  }
  const int np = num_pred[b];
  float last = __shfl(c, np-1, 64);
  float denom = last + 1e-6f;
  float cjm = __shfl(c, (l==0 ? 0 : l-1), 64);
  float val = 0.f;
  if (l >= 1 && l <= 32 && (l-1) < np) val = cjm / denom;
  if (l == np + 1) val += 1.f;
  if (l < 34) out[(size_t)b*419 + l] = val;
  float ta = 0.f, tb = 0.f, tc = 0.f;
  for (int z = l; z < 128; z += 64){
    float ga = out[(size_t)b*419 + 162 + z];
    float tu = fmaxf(out[(size_t)b*419 + 290 + z], 1e-35f);
    ta += tu*tu; tb += ga*ga; tc += -2.f*logf(tu);
  }
  float v = ta + tb + tc;
  #pragma unroll
  for (int off=1; off<64; off<<=1) v += __shfl_xor(v, off, 64);
  if (l == 0) out[(size_t)b*419 + 418] = 0.5f*(v - 128.f);
}

extern "C" void kernel_launch(void* const* d_in, const int* in_sizes, int n_in,
                              void* d_out, int out_size, void* d_ws, size_t ws_size,
                              hipStream_t stream)
{
  (void)in_sizes; (void)n_in; (void)out_size; (void)ws_size;
  const float* d_t    = (const float*)d_in[0];
  const float* d_l    = (const float*)d_in[1];
  const int*   d_emb  = (const int*)  d_in[2];
  const int*   numprd = (const int*)  d_in[4];
  const float* poi    = (const float*)d_in[5];
  const float* W_time = (const float*)d_in[6];
  const float* W_space= (const float*)d_in[7];
  const float* agg    = (const float*)d_in[8];
  const float* Wqkv   = (const float*)d_in[9];
  const float* bqkv   = (const float*)d_in[10];
  const float* Wo     = (const float*)d_in[11];
  const float* bo     = (const float*)d_in[12];
  const float* ln1g   = (const float*)d_in[13];
  const float* ln1b   = (const float*)d_in[14];
  const float* W1     = (const float*)d_in[15];
  const float* b1     = (const float*)d_in[16];
  const float* W2     = (const float*)d_in[17];
  const float* b2     = (const float*)d_in[18];
  const float* ln2g   = (const float*)d_in[19];
  const float* ln2b   = (const float*)d_in[20];
  const float* Wg     = (const float*)d_in[21];
  const float* bg     = (const float*)d_in[22];
  const float* Wt     = (const float*)d_in[23];
  const float* bt     = (const float*)d_in[24];
  const float* Whh    = (const float*)d_in[26];
  const float* bih    = (const float*)d_in[27];
  const float* bhh    = (const float*)d_in[28];
  const float* Wfc    = (const float*)d_in[29];
  const float* bfc    = (const float*)d_in[30];
  float* out = (float*)d_out;

  char* ws = (char*)d_ws;
  size_t off = 0;
  auto alloc = [&](size_t bytes){ size_t o = off; off += (bytes + 255) & ~(size_t)255; return o; };
  ushort* xb    = (ushort*)(ws + alloc((size_t)MM*128*2));
  ushort* qkv   = (ushort*)(ws + alloc((size_t)MM*384*2));
  ushort* aob   = (ushort*)(ws + alloc((size_t)MM*128*2));
  ushort* wqkvb = (ushort*)(ws + alloc((size_t)LL*384*128*2));
  ushort* wob   = (ushort*)(ws + alloc((size_t)LL*128*128*2));
  ushort* w1b   = (ushort*)(ws + alloc((size_t)LL*256*128*2));
  ushort* w2b   = (ushort*)(ws + alloc((size_t)LL*128*256*2));
  ushort* whhb  = (ushort*)(ws + alloc((size_t)384*128*2));
  float*  ctxws = (float*) (ws + alloc(128*128*4));
  float*  deltas= (float*) (ws + alloc(128*32*4));

  const int n0 = LL*384*128, n1 = LL*128*128, n2 = LL*256*128, n3 = LL*128*256, n4 = 384*128;
  k_f2b5<<<(n0+n1+n2+n3+n4+255)/256,256,0,stream>>>(Wqkv,wqkvb,n0, Wo,wob,n1, W1,w1b,n2, W2,w2b,n3, Whh,whhb,n4);
  k_embed<<<(MM*DD)/256,256,0,stream>>>(d_t, d_l, d_emb, poi, W_time, W_space, agg, xb);

  for (int li = 0; li < LL; li++){
    k_gemm2<false><<<MM/128,512,0,stream>>>(xb, wqkvb + li*384*128, bqkv + li*384, qkv, 384);
    k_attn<<<BB*HH,512,0,stream>>>(qkv, aob);
    k_gemm_ln<<<MM/128,512,0,stream>>>(aob, wob + li*128*128, bo + li*128, xb,
                                       ln1g + li*128, ln1b + li*128, 128);
    k_ffn<<<MM/128,512,0,stream>>>(xb, w1b + li*256*128, b1 + li*256,
                                   w2b + li*128*256, b2 + li*128, xb,
                                   ln2g + li*128, ln2b + li*128);
  }

  k_ctx<<<128,256,0,stream>>>(xb, Wg, bg, Wt, bt, out, ctxws);
  k_gru<<<8,512,0,stream>>>(ctxws, whhb, bih, bhh, Wfc, bfc, deltas);
  k_final<<<128,64,0,stream>>>(deltas, numprd, out);
}